// Round 2
// baseline (396.372 us; speedup 1.0000x reference)
//
#include <hip/hip_runtime.h>
#include <hip/hip_bf16.h>
#include <stdint.h>

typedef __attribute__((ext_vector_type(4))) float f32x4;
typedef __attribute__((ext_vector_type(16))) float f32x16;
typedef __attribute__((ext_vector_type(8))) short bf16x8;
typedef __attribute__((ext_vector_type(4))) uint32_t u32x4;

#define KD 512
#define ND 512

// pack two fp32 -> one u32 of two bf16 (round-half-away via +0x8000; v_perm
// grabs the high 16 bits of each)
__device__ __forceinline__ uint32_t pk_bf16(float lo, float hi) {
  uint32_t ulo = __float_as_uint(lo) + 0x8000u;
  uint32_t uhi = __float_as_uint(hi) + 0x8000u;
  return __builtin_amdgcn_perm(uhi, ulo, 0x07060302u);
}

// 8 consecutive-k fp32 (two f32x4) -> one bf16x8 MFMA fragment
__device__ __forceinline__ bf16x8 pack8(f32x4 r0, f32x4 r1) {
  u32x4 p = {pk_bf16(r0.x, r0.y), pk_bf16(r0.z, r0.w),
             pk_bf16(r1.x, r1.y), pk_bf16(r1.z, r1.w)};
  union { u32x4 u; bf16x8 b; } c;
  c.u = p;
  return c.b;
}

// Transpose + RNE-convert w (512x512 fp32, w[k][d]) -> wt[d][k] bf16 in d_ws.
__global__ void wt_kernel(const float* __restrict__ w, uint16_t* __restrict__ wt) {
  __shared__ float tile[32][33];
  const int bx = blockIdx.x, by = blockIdx.y;
  const int tx = threadIdx.x, ty = threadIdx.y;  // (32, 8)
#pragma unroll
  for (int i = 0; i < 32; i += 8)
    tile[ty + i][tx] = w[(bx * 32 + ty + i) * ND + by * 32 + tx];
  __syncthreads();
#pragma unroll
  for (int i = 0; i < 32; i += 8) {
    uint32_t u = __float_as_uint(tile[tx][ty + i]);
    uint32_t r = (u + 0x7FFFu + ((u >> 16) & 1u)) >> 16;  // RNE
    wt[(by * 32 + ty + i) * KD + bx * 32 + tx] = (uint16_t)r;
  }
}

// Barrier-free, LDS-free register GEMM.
// C[m,:] = A[perm(m),:] @ W   (A = x flat 65536x512 fp32, W via wt bf16)
// Block: 4 independent waves, tile 64 rows x 256 cols; wave tile 64x64 via
// 2x2 of mfma_f32_32x32x16_bf16. A-frags straight from global (depth-2
// prefetch), W-frags straight from L2-resident wt (depth-1 double buffer).
__global__ __launch_bounds__(256, 3) void gemm_kernel(
    const float* __restrict__ x, const uint16_t* __restrict__ wt,
    float* __restrict__ out) {
  const int tid = threadIdx.x;
  const int lane = tid & 63;
  const int wid = tid >> 6;
  const int l31 = lane & 31, hi = lane >> 5;

  // bijective XCD swizzle (2048 % 8 == 0): nh fastest so the 2 n-halves of a
  // row-group run adjacently on one XCD (A L2-reuse), then consecutive mt.
  const int bid = blockIdx.x;
  const int logical = (bid & 7) * 256 + (bid >> 3);
  const int nh = logical & 1;
  const int mt = logical >> 1;
  const int m0 = mt * 64;
  const int n0 = nh * 256 + wid * 64;

  const char* xb = (const char*)x;
  const char* wb = (const char*)wt;

  // patch-expansion perm folded into A row addr: within each 64-row block,
  // output row u reads input row ((u&31)<<1)|(u>>5); u = tm*32+l31 -> 2*l31+tm
  uint32_t aOff[2], wOff[2];
#pragma unroll
  for (int tm = 0; tm < 2; ++tm)
    aOff[tm] = (uint32_t)(m0 + l31 * 2 + tm) * (KD * 4) + hi * 32;
#pragma unroll
  for (int tn = 0; tn < 2; ++tn)
    wOff[tn] = (uint32_t)(n0 + tn * 32 + l31) * (KD * 2) + hi * 16;

  f32x16 acc[2][2];
#pragma unroll
  for (int tm = 0; tm < 2; ++tm)
#pragma unroll
    for (int tn = 0; tn < 2; ++tn)
#pragma unroll
      for (int e = 0; e < 16; ++e) acc[tm][tn][e] = 0.f;

  // prologue: A for ks=0,1 (depth-2), W for ks=0
  f32x4 raw[2][2][2];  // [parity][tm][half]
  bf16x8 wf[2][2];     // [parity][tn]
#pragma unroll
  for (int tm = 0; tm < 2; ++tm) {
    raw[0][tm][0] = *(const f32x4*)(xb + aOff[tm] + 0);
    raw[0][tm][1] = *(const f32x4*)(xb + aOff[tm] + 16);
    raw[1][tm][0] = *(const f32x4*)(xb + aOff[tm] + 64);
    raw[1][tm][1] = *(const f32x4*)(xb + aOff[tm] + 80);
  }
#pragma unroll
  for (int tn = 0; tn < 2; ++tn)
    wf[0][tn] = *(const bf16x8*)(wb + wOff[tn]);

#pragma unroll
  for (int ks = 0; ks < 32; ++ks) {
    const int p = ks & 1;
    // convert this K-step's A to bf16 (waits counted-vmcnt on loads from ks-2)
    bf16x8 af0 = pack8(raw[p][0][0], raw[p][0][1]);
    bf16x8 af1 = pack8(raw[p][1][0], raw[p][1][1]);
    // refill the just-consumed A regs for ks+2
    if (ks + 2 < 32) {
#pragma unroll
      for (int tm = 0; tm < 2; ++tm) {
        raw[p][tm][0] = *(const f32x4*)(xb + aOff[tm] + (ks + 2) * 64);
        raw[p][tm][1] = *(const f32x4*)(xb + aOff[tm] + (ks + 2) * 64 + 16);
      }
    }
    // W fragments for ks+1 into the other parity buffer
    if (ks + 1 < 32) {
#pragma unroll
      for (int tn = 0; tn < 2; ++tn)
        wf[(ks + 1) & 1][tn] =
            *(const bf16x8*)(wb + wOff[tn] + (ks + 1) * 32);
    }
    // operand swap: D."col"(lane&31) = x-row, D."row"(reg-map) = W-col
    acc[0][0] = __builtin_amdgcn_mfma_f32_32x32x16_bf16(wf[p][0], af0, acc[0][0], 0, 0, 0);
    acc[0][1] = __builtin_amdgcn_mfma_f32_32x32x16_bf16(wf[p][1], af0, acc[0][1], 0, 0, 0);
    acc[1][0] = __builtin_amdgcn_mfma_f32_32x32x16_bf16(wf[p][0], af1, acc[1][0], 0, 0, 0);
    acc[1][1] = __builtin_amdgcn_mfma_f32_32x32x16_bf16(wf[p][1], af1, acc[1][1], 0, 0, 0);
  }

  // epilogue: 32x32 C/D map: col(lane&31)=x-row, row=(reg&3)+8*(reg>>2)+4*hi=W-col
#pragma unroll
  for (int tm = 0; tm < 2; ++tm) {
    float* op = out + (size_t)(m0 + tm * 32 + l31) * ND;
#pragma unroll
    for (int tn = 0; tn < 2; ++tn) {
#pragma unroll
      for (int q = 0; q < 4; ++q) {
        f32x4 v = {acc[tm][tn][q * 4 + 0], acc[tm][tn][q * 4 + 1],
                   acc[tm][tn][q * 4 + 2], acc[tm][tn][q * 4 + 3]};
        *(f32x4*)(op + n0 + tn * 32 + q * 8 + hi * 4) = v;
      }
    }
  }
}

extern "C" void kernel_launch(void* const* d_in, const int* in_sizes, int n_in,
                              void* d_out, int out_size, void* d_ws, size_t ws_size,
                              hipStream_t stream) {
  const float* x = (const float*)d_in[0];  // (32, 1024, 1024) fp32
  const float* w = (const float*)d_in[1];  // (512, 512) fp32
  float* out = (float*)d_out;              // (32, 2048, 512) fp32
  uint16_t* wt = (uint16_t*)d_ws;          // 512x512 bf16 = 512 KB scratch

  wt_kernel<<<dim3(16, 16), dim3(32, 8), 0, stream>>>(w, wt);
  gemm_kernel<<<dim3(2048), dim3(256), 0, stream>>>(x, wt, out);
}

// Round 3
// 284.925 us; speedup vs baseline: 1.3911x; 1.3911x over previous
//
#include <hip/hip_runtime.h>
#include <hip/hip_bf16.h>
#include <stdint.h>

typedef __attribute__((ext_vector_type(4))) float f32x4;
typedef __attribute__((ext_vector_type(16))) float f32x16;
typedef __attribute__((ext_vector_type(8))) short bf16x8;
typedef __attribute__((ext_vector_type(4))) uint32_t u32x4;

#define KD 512
#define ND 512

// pack two fp32 -> one u32 of two bf16 (round-half-away via +0x8000; v_perm
// grabs the high 16 bits of each)
__device__ __forceinline__ uint32_t pk_bf16(float lo, float hi) {
  uint32_t ulo = __float_as_uint(lo) + 0x8000u;
  uint32_t uhi = __float_as_uint(hi) + 0x8000u;
  return __builtin_amdgcn_perm(uhi, ulo, 0x07060302u);
}

// Transpose + RNE-convert w (512x512 fp32, w[k][d]) -> wt[d][k] bf16 in d_ws.
__global__ void wt_kernel(const float* __restrict__ w, uint16_t* __restrict__ wt) {
  __shared__ float tile[32][33];
  const int bx = blockIdx.x, by = blockIdx.y;
  const int tx = threadIdx.x, ty = threadIdx.y;  // (32, 8)
#pragma unroll
  for (int i = 0; i < 32; i += 8)
    tile[ty + i][tx] = w[(bx * 32 + ty + i) * ND + by * 32 + tx];
  __syncthreads();
#pragma unroll
  for (int i = 0; i < 32; i += 8) {
    uint32_t u = __float_as_uint(tile[tx][ty + i]);
    uint32_t r = (u + 0x7FFFu + ((u >> 16) & 1u)) >> 16;  // RNE
    wt[(by * 32 + ty + i) * KD + bx * 32 + tx] = (uint16_t)r;
  }
}

// One-barrier panel GEMM.
// Block: 64 output rows x all 512 cols. Phase 1: stage the full 64x512 fp32
// A-panel (rows pre-permuted) as bf16 into LDS via 16 independent
// load->pack->ds_write chains per thread (BW-bound, deep MLP). Phase 2 (after
// ONE barrier): 4 waves, each 64 rows x 128 cols via 2x4 of
// mfma_f32_32x32x16_bf16; af from swizzled LDS, W-frags from L2-resident wt
// with depth-2 prefetch. No per-K-step barriers anywhere.
__global__ __launch_bounds__(256, 2) void gemm_kernel(
    const float* __restrict__ x, const uint16_t* __restrict__ wt,
    float* __restrict__ out) {
  __shared__ uint16_t As[64 * 512];  // bf16, row stride 1024B, 16B-slot XOR swizzle

  const int tid = threadIdx.x;
  const int lane = tid & 63;
  const int l31 = lane & 31, hi = lane >> 5;
  const int wid = tid >> 6;  // n-slice: cols [wid*128, wid*128+128)
  const int m0 = blockIdx.x * 64;

  // ---- Phase 1: stage A-panel (permuted rows), fp32 -> bf16 LDS ----
  {
    const int r = tid >> 2;   // 0..63 output-local row
    const int c0 = tid & 3;   // 32B-chunk lane within row
    // patch-expansion perm folded into source row address
    const int aRow = m0 + ((r & 31) << 1) + (r >> 5);
    const char* src = (const char*)x + (size_t)aRow * (KD * 4) + c0 * 32;
    char* dst = (char*)As + r * 1024;
    const int rx = (r & 7) << 1;  // slot-XOR for this row
#pragma unroll 4
    for (int i = 0; i < 16; ++i) {
      const int c = c0 + i * 4;  // 16B bf16 slot index 0..63
      f32x4 lo = *(const f32x4*)(src + i * 128);
      f32x4 h4 = *(const f32x4*)(src + i * 128 + 16);
      u32x4 p = {pk_bf16(lo.x, lo.y), pk_bf16(lo.z, lo.w),
                 pk_bf16(h4.x, h4.y), pk_bf16(h4.z, h4.w)};
      *(u32x4*)(dst + (c ^ rx) * 16) = p;
    }
  }
  __syncthreads();  // the only barrier

  // ---- Phase 2: barrier-free MFMA loop ----
  const char* wb = (const char*)wt;
  uint32_t wOff[4];
#pragma unroll
  for (int tn = 0; tn < 4; ++tn)
    wOff[tn] = (uint32_t)(wid * 128 + tn * 32 + l31) * (KD * 2) + hi * 16;

  uint32_t aBase[2], aXor[2];
#pragma unroll
  for (int tm = 0; tm < 2; ++tm) {
    const int u = tm * 32 + l31;
    aBase[tm] = u * 1024;
    aXor[tm] = (u & 7) << 1;
  }

  f32x16 acc[2][4];
#pragma unroll
  for (int tm = 0; tm < 2; ++tm)
#pragma unroll
    for (int tn = 0; tn < 4; ++tn)
#pragma unroll
      for (int e = 0; e < 16; ++e) acc[tm][tn][e] = 0.f;

  bf16x8 wf[2][4];
#pragma unroll
  for (int tn = 0; tn < 4; ++tn)
    wf[0][tn] = *(const bf16x8*)(wb + wOff[tn]);  // ks=0

#pragma unroll 4
  for (int ks = 0; ks < 32; ++ks) {
    const int p = ks & 1;
    if (ks + 1 < 32) {
#pragma unroll
      for (int tn = 0; tn < 4; ++tn)
        wf[p ^ 1][tn] = *(const bf16x8*)(wb + wOff[tn] + (ks + 1) * 32);
    }
    bf16x8 af[2];
#pragma unroll
    for (int tm = 0; tm < 2; ++tm) {
      const uint32_t s = (uint32_t)(2 * ks + hi) ^ aXor[tm];
      af[tm] = *(const bf16x8*)((const char*)As + aBase[tm] + s * 16);
    }
#pragma unroll
    for (int tm = 0; tm < 2; ++tm)
#pragma unroll
      for (int tn = 0; tn < 4; ++tn)
        acc[tm][tn] = __builtin_amdgcn_mfma_f32_32x32x16_bf16(
            wf[p][tn], af[tm], acc[tm][tn], 0, 0, 0);
  }

  // ---- epilogue: D col(lane&31)=x-row, row=(r&3)+8*(r>>2)+4*hi = W-col ----
#pragma unroll
  for (int tm = 0; tm < 2; ++tm) {
    float* op = out + (size_t)(m0 + tm * 32 + l31) * ND + wid * 128;
#pragma unroll
    for (int tn = 0; tn < 4; ++tn) {
#pragma unroll
      for (int q = 0; q < 4; ++q) {
        f32x4 v = {acc[tm][tn][q * 4 + 0], acc[tm][tn][q * 4 + 1],
                   acc[tm][tn][q * 4 + 2], acc[tm][tn][q * 4 + 3]};
        *(f32x4*)(op + tn * 32 + q * 8 + hi * 4) = v;
      }
    }
  }
}

extern "C" void kernel_launch(void* const* d_in, const int* in_sizes, int n_in,
                              void* d_out, int out_size, void* d_ws, size_t ws_size,
                              hipStream_t stream) {
  const float* x = (const float*)d_in[0];  // (32, 1024, 1024) fp32
  const float* w = (const float*)d_in[1];  // (512, 512) fp32
  float* out = (float*)d_out;              // (32, 2048, 512) fp32
  uint16_t* wt = (uint16_t*)d_ws;          // 512x512 bf16 = 512 KB scratch

  wt_kernel<<<dim3(16, 16), dim3(32, 8), 0, stream>>>(w, wt);
  gemm_kernel<<<dim3(1024), dim3(256), 0, stream>>>(x, wt, out);
}